// Round 12
// baseline (444.791 us; speedup 1.0000x reference)
//
#include <hip/hip_runtime.h>
#include <hip/hip_bf16.h>
#include <stdint.h>

typedef __attribute__((ext_vector_type(8))) short bf16x8;
typedef __attribute__((ext_vector_type(4))) float f32x4;

#define PH 130
#define NT 72          // K tiles: 9 taps x 256 ci / BK=32

__device__ __forceinline__ short f2bf(float f) {
  uint32_t u = __builtin_bit_cast(uint32_t, f);
  u = (u + 0x7FFFu + ((u >> 16) & 1u)) >> 16;
  return (short)u;
}

__device__ __forceinline__ uint32_t pack2bf(float lo, float hi) {
  return ((uint32_t)(uint16_t)f2bf(hi) << 16) | (uint16_t)f2bf(lo);
}

__device__ __forceinline__ void gload16(const void* g, void* l) {
  __builtin_amdgcn_global_load_lds(
      (const __attribute__((address_space(1))) void*)g,
      (__attribute__((address_space(3))) void*)l, 16, 0, 0);
}

// ---------------------------------------------------------------------------
// Repack W [256co][256ci][3][3] f32 -> A [co][tap*256+ci] bf16 (tap-major K)
// ---------------------------------------------------------------------------
__global__ void wpack(const float* __restrict__ W, short* __restrict__ A) {
  int tid = blockIdx.x * 256 + threadIdx.x;
  if (tid >= 256 * 2304) return;
  int co = tid / 2304;
  int r  = tid - co * 2304;
  int tap = r >> 8, ci = r & 255;
  A[tid] = f2bf(W[((size_t)(co * 256 + ci)) * 9 + tap]);
}

// ---------------------------------------------------------------------------
// FIR upsample v3: one block per output-row PAIR (p=2t,2t+1), sharing 3
// x-rows. Row-fold in registers at load; col pass per pair.
// hT[b][p'][q'][ci] bf16, p',q' in [0,130), interior = h[p'-1][q'-1].
// ---------------------------------------------------------------------------
__global__ void fir_up(const float* __restrict__ x, short* __restrict__ hT) {
  const int bt = blockIdx.x;
  const int b = bt / 65, t = bt - b * 65;
  const int ci0 = blockIdx.y << 6;
  const int tid = threadIdx.x;

  if (t == 64) {                           // pad rows pp=0 and pp=129
    short* r0 = hT + ((size_t)(b * PH + 0) * PH) * 256 + ci0;
    short* r1 = hT + ((size_t)(b * PH + 129) * PH) * 256 + ci0;
    for (int idx = tid; idx < PH * 32; idx += 256) {
      int qp = idx >> 5, c2 = (idx & 31) * 2;
      *(uint32_t*)&r0[(size_t)qp * 256 + c2] = 0u;
      *(uint32_t*)&r1[(size_t)qp * 256 + c2] = 0u;
    }
    return;
  }

  __shared__ float F[2][64][65];           // folded rows [pair r][j][ci] (+1 pad)
#pragma unroll
  for (int it = 0; it < 4; ++it) {
    int idx = it * 256 + tid;              // ci = idx>>4, j-quad = idx&15
    int ci = idx >> 4, jq = idx & 15;
    const float* base = &x[((size_t)(b * 256 + ci0 + ci) * 64) * 64 + jq * 4];
    f32x4 vm = {0.f, 0.f, 0.f, 0.f}, vp = {0.f, 0.f, 0.f, 0.f};
    f32x4 v0 = *(const f32x4*)(base + (size_t)t * 64);
    if (t >= 1)  vm = *(const f32x4*)(base + (size_t)(t - 1) * 64);
    if (t <= 62) vp = *(const f32x4*)(base + (size_t)(t + 1) * 64);
#pragma unroll
    for (int e = 0; e < 4; ++e) {
      F[0][jq * 4 + e][ci] = 0.25f * vm[e] + 0.75f * v0[e];
      F[1][jq * 4 + e][ci] = 0.75f * v0[e] + 0.25f * vp[e];
    }
  }
  __syncthreads();

  const int c2 = (tid & 31) * 2;
  const int qg = tid >> 5;
#pragma unroll
  for (int r = 0; r < 2; ++r) {
    short* outrow = hT + ((size_t)(b * PH + (2 * t + 1 + r)) * PH) * 256 + ci0;
    for (int qp = qg; qp < PH; qp += 8) {
      uint32_t out = 0u;
      if (qp >= 1 && qp <= 128) {
        int q = qp - 1;
        int par = q & 1;
        int jb = (q >> 1) - 1 + par;
        float wc0 = par ? 0.75f : 0.25f;
        float wc1 = par ? 0.25f : 0.75f;
        float v00 = 0.f, v01 = 0.f, v10 = 0.f, v11 = 0.f;
        if (jb >= 0)     { v00 = F[r][jb][c2];     v01 = F[r][jb][c2 + 1]; }
        if (jb + 1 < 64) { v10 = F[r][jb + 1][c2]; v11 = F[r][jb + 1][c2 + 1]; }
        out = pack2bf(wc0 * v00 + wc1 * v10, wc0 * v01 + wc1 * v11);
      }
      *(uint32_t*)&outrow[(size_t)qp * 256 + c2] = out;
    }
  }
}

// ---------------------------------------------------------------------------
// Implicit GEMM, LDS-bandwidth-optimized 3-blocks/CU variant:
// BM=128 (one (b,p) row) x BN=128 co, BK=32 (NT=72), 256 threads = 4 waves
// (2M x 2N), wave tile 64q x 64co (acc 4x4 f32x4 = 64 VGPR,
// 0.5 ds_reads/MFMA vs R11's 0.75). LDS: A+B ring-3 = 48KB -> 3 blocks/CU.
// Per K-tile: 8 ds_read_b128 + stage(t+2) (4 gloads) + 16 MFMA + ONE barrier;
// gate vmcnt(4) (forces t+1, leaves t+2 in flight; never 0 mid-loop).
// 64B-row swizzle: phys = L ^ (((L>>7)&3)<<4)  (involution, bits 4-5; frag
// reads land 2 lanes/bank-group = free). Applied both sides (rule 21).
// ---------------------------------------------------------------------------
__global__ __launch_bounds__(256, 3) void conv3x3_gemm(
    const short* __restrict__ hT, const short* __restrict__ Wp,
    const float* __restrict__ bias, float* __restrict__ y) {
  __shared__ short ldsA[3][4096];          // 3 x 8KB [128 rows][32 k]
  __shared__ short ldsB[3][4096];
  const int tid = threadIdx.x;
  const int lane = tid & 63, w = tid >> 6;
  const int wm = w >> 1, wn = w & 1;       // 2 M-halves x 2 N-halves

  const int bid = blockIdx.x;
  const int tau = (bid & 7) * 512 + (bid >> 3);  // XCD swizzle, 4096%8==0
  const int mt = tau >> 1, nh = tau & 1;         // M-tile, N-half
  const int b = mt >> 7, p = mt & 127;

  // --- staging sources (rule 21 pre-swizzle): dest o = i*4096 + tid*16 ---
  const short* srcA[2];
  const short* srcB[2];
#pragma unroll
  for (int i = 0; i < 2; ++i) {
    int o = i * 4096 + tid * 16;
    int L = o ^ (((o >> 7) & 3) << 4);
    int row = L >> 6, kk = (L & 63) >> 1;        // row in [0,128), k elem
    srcA[i] = hT + ((size_t)((b * PH + p) * PH + row)) * 256 + kk;
    srcB[i] = Wp + (size_t)(nh * 128 + row) * 2304 + kk;
  }

  auto offA = [&](int t) {
    int tap = t >> 3, ci0 = (t & 7) << 5;
    int dm = (tap >= 6) ? 2 : (tap >= 3) ? 1 : 0;
    int dn = tap - 3 * dm;
    return (dm * PH + dn) * 256 + ci0;
  };
  auto offB = [&](int t) { return (t >> 3) * 256 + ((t & 7) << 5); };

  auto stage = [&](int t) {                // A+B, 4 gloads, buf t%3
    int buf = t % 3;
    int oa = offA(t), ob = offB(t);
#pragma unroll
    for (int i = 0; i < 2; ++i) {
      gload16(srcA[i] + oa, &ldsA[buf][i * 2048] + (tid << 3));
      gload16(srcB[i] + ob, &ldsB[buf][i * 2048] + (tid << 3));
    }
  };

  // --- swizzled frag bases (bytes); XOR lane-constant (row parity only) ---
  const int aP = ((wm * 64 + (lane & 15)) * 64 + (lane >> 4) * 16)
                 ^ ((((lane & 15) >> 1) & 3) << 4);
  const int bP = ((wn * 64 + (lane & 15)) * 64 + (lane >> 4) * 16)
                 ^ ((((lane & 15) >> 1) & 3) << 4);

  f32x4 acc[4][4];
#pragma unroll
  for (int m = 0; m < 4; ++m)
#pragma unroll
    for (int n = 0; n < 4; ++n) acc[m][n] = (f32x4){0.f, 0.f, 0.f, 0.f};

  // --- prologue: stage(0), stage(1) = 8 loads; vmcnt(4) forces tile 0 ---
  stage(0); stage(1);
  asm volatile("s_waitcnt vmcnt(4)" ::: "memory");
  __builtin_amdgcn_s_barrier();

  for (int t = 0; t < NT; ++t) {
    const char* LA = (const char*)&ldsA[t % 3][0];
    const char* LB = (const char*)&ldsB[t % 3][0];

    bf16x8 a_[4], b_[4];
#pragma unroll
    for (int m = 0; m < 4; ++m) a_[m] = *(const bf16x8*)(LA + aP + m * 1024);
#pragma unroll
    for (int n = 0; n < 4; ++n) b_[n] = *(const bf16x8*)(LB + bP + n * 1024);
    if (t + 2 < NT) stage(t + 2);
    asm volatile("s_waitcnt lgkmcnt(0)" ::: "memory");
    __builtin_amdgcn_s_setprio(1);
#pragma unroll
    for (int m = 0; m < 4; ++m)
#pragma unroll
      for (int n = 0; n < 4; ++n)
        acc[m][n] = __builtin_amdgcn_mfma_f32_16x16x32_bf16(a_[m], b_[n], acc[m][n], 0, 0, 0);
    __builtin_amdgcn_s_setprio(0);
    if (t < NT - 2)       asm volatile("s_waitcnt vmcnt(4)" ::: "memory");
    else if (t == NT - 2) asm volatile("s_waitcnt vmcnt(0)" ::: "memory");
    if (t < NT - 1) __builtin_amdgcn_s_barrier();
  }

  // ---- epilogue: D row = q, col = co; p fixed ----
#pragma unroll
  for (int n = 0; n < 4; ++n) {
    int co = nh * 128 + wn * 64 + n * 16 + (lane & 15);
    float bv = bias[co];
    float* yp = y + (((size_t)(b * 256 + co)) * 128 + p) * 128;
#pragma unroll
    for (int m = 0; m < 4; ++m) {
      int q0 = wm * 64 + m * 16 + ((lane >> 4) << 2);
      f32x4 vv = acc[m][n];
      vv[0] += bv; vv[1] += bv; vv[2] += bv; vv[3] += bv;
      *(f32x4*)(yp + q0) = vv;
    }
  }
}

// ---------------------------------------------------------------------------
extern "C" void kernel_launch(void* const* d_in, const int* in_sizes, int n_in,
                              void* d_out, int out_size, void* d_ws, size_t ws_size,
                              hipStream_t stream) {
  const float* x    = (const float*)d_in[0];
  const float* W    = (const float*)d_in[1];
  const float* bias = (const float*)d_in[2];
  float* y = (float*)d_out;

  const size_t hT_bytes = (size_t)16 * PH * PH * 256 * 2;   // 138,444,800
  const size_t A_bytes  = (size_t)256 * 2304 * 2;           //   1,179,648
  if (ws_size < hT_bytes + A_bytes) return;

  short* hT = (short*)d_ws;
  short* Wp = (short*)((char*)d_ws + hT_bytes);

  wpack<<<(256 * 2304 + 255) / 256, 256, 0, stream>>>(W, Wp);
  dim3 g1(16 * 65, 4);
  fir_up<<<g1, 256, 0, stream>>>(x, hT);
  conv3x3_gemm<<<4096, 256, 0, stream>>>(hT, Wp, bias, y);
}

// Round 13
// 402.202 us; speedup vs baseline: 1.1059x; 1.1059x over previous
//
#include <hip/hip_runtime.h>
#include <hip/hip_bf16.h>
#include <stdint.h>

typedef __attribute__((ext_vector_type(8))) short bf16x8;
typedef __attribute__((ext_vector_type(4))) float f32x4;

#define PH 130
#define NT 72          // K tiles: 9 taps x 256 ci / BK=32

__device__ __forceinline__ short f2bf(float f) {
  uint32_t u = __builtin_bit_cast(uint32_t, f);
  u = (u + 0x7FFFu + ((u >> 16) & 1u)) >> 16;
  return (short)u;
}

__device__ __forceinline__ uint32_t pack2bf(float lo, float hi) {
  return ((uint32_t)(uint16_t)f2bf(hi) << 16) | (uint16_t)f2bf(lo);
}

__device__ __forceinline__ void gload16(const void* g, void* l) {
  __builtin_amdgcn_global_load_lds(
      (const __attribute__((address_space(1))) void*)g,
      (__attribute__((address_space(3))) void*)l, 16, 0, 0);
}

// ---------------------------------------------------------------------------
// Repack W [256co][256ci][3][3] f32 -> A [co][tap*256+ci] bf16 (tap-major K)
// ---------------------------------------------------------------------------
__global__ void wpack(const float* __restrict__ W, short* __restrict__ A) {
  int tid = blockIdx.x * 256 + threadIdx.x;
  if (tid >= 256 * 2304) return;
  int co = tid / 2304;
  int r  = tid - co * 2304;
  int tap = r >> 8, ci = r & 255;
  A[tid] = f2bf(W[((size_t)(co * 256 + ci)) * 9 + tap]);
}

// ---------------------------------------------------------------------------
// FIR upsample v3: one block per output-row PAIR (p=2t,2t+1), sharing 3
// x-rows. Row-fold in registers at load; col pass per pair.
// hT[b][p'][q'][ci] bf16, p',q' in [0,130), interior = h[p'-1][q'-1].
// ---------------------------------------------------------------------------
__global__ void fir_up(const float* __restrict__ x, short* __restrict__ hT) {
  const int bt = blockIdx.x;
  const int b = bt / 65, t = bt - b * 65;
  const int ci0 = blockIdx.y << 6;
  const int tid = threadIdx.x;

  if (t == 64) {                           // pad rows pp=0 and pp=129
    short* r0 = hT + ((size_t)(b * PH + 0) * PH) * 256 + ci0;
    short* r1 = hT + ((size_t)(b * PH + 129) * PH) * 256 + ci0;
    for (int idx = tid; idx < PH * 32; idx += 256) {
      int qp = idx >> 5, c2 = (idx & 31) * 2;
      *(uint32_t*)&r0[(size_t)qp * 256 + c2] = 0u;
      *(uint32_t*)&r1[(size_t)qp * 256 + c2] = 0u;
    }
    return;
  }

  __shared__ float F[2][64][65];           // folded rows [pair r][j][ci] (+1 pad)
#pragma unroll
  for (int it = 0; it < 4; ++it) {
    int idx = it * 256 + tid;              // ci = idx>>4, j-quad = idx&15
    int ci = idx >> 4, jq = idx & 15;
    const float* base = &x[((size_t)(b * 256 + ci0 + ci) * 64) * 64 + jq * 4];
    f32x4 vm = {0.f, 0.f, 0.f, 0.f}, vp = {0.f, 0.f, 0.f, 0.f};
    f32x4 v0 = *(const f32x4*)(base + (size_t)t * 64);
    if (t >= 1)  vm = *(const f32x4*)(base + (size_t)(t - 1) * 64);
    if (t <= 62) vp = *(const f32x4*)(base + (size_t)(t + 1) * 64);
#pragma unroll
    for (int e = 0; e < 4; ++e) {
      F[0][jq * 4 + e][ci] = 0.25f * vm[e] + 0.75f * v0[e];
      F[1][jq * 4 + e][ci] = 0.75f * v0[e] + 0.25f * vp[e];
    }
  }
  __syncthreads();

  const int c2 = (tid & 31) * 2;
  const int qg = tid >> 5;
#pragma unroll
  for (int r = 0; r < 2; ++r) {
    short* outrow = hT + ((size_t)(b * PH + (2 * t + 1 + r)) * PH) * 256 + ci0;
    for (int qp = qg; qp < PH; qp += 8) {
      uint32_t out = 0u;
      if (qp >= 1 && qp <= 128) {
        int q = qp - 1;
        int par = q & 1;
        int jb = (q >> 1) - 1 + par;
        float wc0 = par ? 0.75f : 0.25f;
        float wc1 = par ? 0.25f : 0.75f;
        float v00 = 0.f, v01 = 0.f, v10 = 0.f, v11 = 0.f;
        if (jb >= 0)     { v00 = F[r][jb][c2];     v01 = F[r][jb][c2 + 1]; }
        if (jb + 1 < 64) { v10 = F[r][jb + 1][c2]; v11 = F[r][jb + 1][c2 + 1]; }
        out = pack2bf(wc0 * v00 + wc1 * v10, wc0 * v01 + wc1 * v11);
      }
      *(uint32_t*)&outrow[(size_t)qp * 256 + c2] = out;
    }
  }
}

// ---------------------------------------------------------------------------
// Implicit GEMM: low-LDS-traffic + high-occupancy variant.
// BM=128 (one (b,p) row) x BN=256 (full co), BK=32 (NT=72), 512 threads =
// 8 waves (2M x 4N), wave tile 64q x 64co (acc 4x4 f32x4 = 64 VGPR,
// 0.5 ds_reads/MFMA). LDS = A ring-3 (3x8KB) + B ring-3 (3x16KB) = 72KB ->
// 2 blocks/CU = 16 waves/CU (R11's latency structure, 33% less read traffic).
// Per K-tile: 8 ds_read_b128/wave + stage(t+2) (3 gloads) + 16 MFMA + ONE
// barrier; gate vmcnt(3) (forces t+1, leaves t+2 in flight; never 0 mid-loop).
// 64B-row swizzle (proven 0-conflict in R12): phys = L ^ (((L>>7)&3)<<4),
// both sides (rule 21); XOR commutes with m*1024 frag steps.
// ---------------------------------------------------------------------------
__global__ __launch_bounds__(512, 4) void conv3x3_gemm(
    const short* __restrict__ hT, const short* __restrict__ Wp,
    const float* __restrict__ bias, float* __restrict__ y) {
  __shared__ short ldsA[3][4096];          // 3 x 8KB  [128 rows][32 k]
  __shared__ short ldsB[3][8192];          // 3 x 16KB [256 rows][32 k]
  const int tid = threadIdx.x;
  const int lane = tid & 63, w = tid >> 6;
  const int wm = w >> 2, wn = w & 3;       // 2 M-halves x 4 N-quarters

  const int bid = blockIdx.x;
  const int tau = (bid & 7) * 256 + (bid >> 3);  // XCD swizzle, 2048%8==0
  const int b = tau >> 7, p = tau & 127;

  // --- staging sources (rule 21 pre-swizzle) ---
  const short* srcA0;
  const short* srcB[2];
  {
    int o = tid * 16;                      // A: one 8KB issue
    int L = o ^ (((o >> 7) & 3) << 4);
    int row = L >> 6, kk = (L & 63) >> 1;
    srcA0 = hT + ((size_t)((b * PH + p) * PH + row)) * 256 + kk;
  }
#pragma unroll
  for (int i = 0; i < 2; ++i) {            // B: two 8KB issues
    int o = i * 8192 + tid * 16;
    int L = o ^ (((o >> 7) & 3) << 4);
    int row = L >> 6, kk = (L & 63) >> 1;  // row in [0,256)
    srcB[i] = Wp + (size_t)row * 2304 + kk;
  }

  auto offA = [&](int t) {
    int tap = t >> 3, ci0 = (t & 7) << 5;
    int dm = (tap >= 6) ? 2 : (tap >= 3) ? 1 : 0;
    int dn = tap - 3 * dm;
    return (dm * PH + dn) * 256 + ci0;
  };
  auto offB = [&](int t) { return (t >> 3) * 256 + ((t & 7) << 5); };

  auto stage = [&](int t) {                // 3 gload issues (A 1 + B 2)
    int buf = t % 3;
    int oa = offA(t), ob = offB(t);
    gload16(srcA0 + oa, &ldsA[buf][0] + (tid << 3));
    gload16(srcB[0] + ob, &ldsB[buf][0] + (tid << 3));
    gload16(srcB[1] + ob, &ldsB[buf][4096] + (tid << 3));
  };

  // --- swizzled frag bases (bytes); reads = base + frag*1024 ---
  int aP, bP;
  {
    int La = (wm * 64 + (lane & 15)) * 64 + (lane >> 4) * 16;
    aP = La ^ (((La >> 7) & 3) << 4);
    int Lb = (wn * 64 + (lane & 15)) * 64 + (lane >> 4) * 16;
    bP = Lb ^ (((Lb >> 7) & 3) << 4);
  }

  f32x4 acc[4][4];
#pragma unroll
  for (int m = 0; m < 4; ++m)
#pragma unroll
    for (int n = 0; n < 4; ++n) acc[m][n] = (f32x4){0.f, 0.f, 0.f, 0.f};

  // --- prologue: stage(0), stage(1) = 6 issues; vmcnt(3) forces tile 0 ---
  stage(0); stage(1);
  asm volatile("s_waitcnt vmcnt(3)" ::: "memory");
  __builtin_amdgcn_s_barrier();

  for (int t = 0; t < NT; ++t) {
    const char* LA = (const char*)&ldsA[t % 3][0];
    const char* LB = (const char*)&ldsB[t % 3][0];

    bf16x8 a_[4], b_[4];
#pragma unroll
    for (int m = 0; m < 4; ++m) a_[m] = *(const bf16x8*)(LA + aP + m * 1024);
#pragma unroll
    for (int n = 0; n < 4; ++n) b_[n] = *(const bf16x8*)(LB + bP + n * 1024);
    if (t + 2 < NT) stage(t + 2);
    asm volatile("s_waitcnt lgkmcnt(0)" ::: "memory");
    __builtin_amdgcn_s_setprio(1);
#pragma unroll
    for (int m = 0; m < 4; ++m)
#pragma unroll
      for (int n = 0; n < 4; ++n)
        acc[m][n] = __builtin_amdgcn_mfma_f32_16x16x32_bf16(a_[m], b_[n], acc[m][n], 0, 0, 0);
    __builtin_amdgcn_s_setprio(0);
    if (t < NT - 2)       asm volatile("s_waitcnt vmcnt(3)" ::: "memory");
    else if (t == NT - 2) asm volatile("s_waitcnt vmcnt(0)" ::: "memory");
    if (t < NT - 1) __builtin_amdgcn_s_barrier();
  }

  // ---- epilogue: D row = q, col = co; p fixed ----
#pragma unroll
  for (int n = 0; n < 4; ++n) {
    int co = wn * 64 + n * 16 + (lane & 15);
    float bv = bias[co];
    float* yp = y + (((size_t)(b * 256 + co)) * 128 + p) * 128;
#pragma unroll
    for (int m = 0; m < 4; ++m) {
      int q0 = wm * 64 + m * 16 + ((lane >> 4) << 2);
      f32x4 vv = acc[m][n];
      vv[0] += bv; vv[1] += bv; vv[2] += bv; vv[3] += bv;
      *(f32x4*)(yp + q0) = vv;
    }
  }
}

// ---------------------------------------------------------------------------
extern "C" void kernel_launch(void* const* d_in, const int* in_sizes, int n_in,
                              void* d_out, int out_size, void* d_ws, size_t ws_size,
                              hipStream_t stream) {
  const float* x    = (const float*)d_in[0];
  const float* W    = (const float*)d_in[1];
  const float* bias = (const float*)d_in[2];
  float* y = (float*)d_out;

  const size_t hT_bytes = (size_t)16 * PH * PH * 256 * 2;   // 138,444,800
  const size_t A_bytes  = (size_t)256 * 2304 * 2;           //   1,179,648
  if (ws_size < hT_bytes + A_bytes) return;

  short* hT = (short*)d_ws;
  short* Wp = (short*)((char*)d_ws + hT_bytes);

  wpack<<<(256 * 2304 + 255) / 256, 256, 0, stream>>>(W, Wp);
  dim3 g1(16 * 65, 4);
  fir_up<<<g1, 256, 0, stream>>>(x, hT);
  conv3x3_gemm<<<2048, 512, 0, stream>>>(hT, Wp, bias, y);
}

// Round 14
// 375.819 us; speedup vs baseline: 1.1835x; 1.0702x over previous
//
#include <hip/hip_runtime.h>
#include <hip/hip_bf16.h>
#include <stdint.h>

typedef __attribute__((ext_vector_type(8))) short bf16x8;
typedef __attribute__((ext_vector_type(4))) float f32x4;

#define PH 130
#define NT 36          // K tiles: 9 taps x 256 ci / BK=64

__device__ __forceinline__ short f2bf(float f) {
  uint32_t u = __builtin_bit_cast(uint32_t, f);
  u = (u + 0x7FFFu + ((u >> 16) & 1u)) >> 16;
  return (short)u;
}

__device__ __forceinline__ uint32_t pack2bf(float lo, float hi) {
  return ((uint32_t)(uint16_t)f2bf(hi) << 16) | (uint16_t)f2bf(lo);
}

__device__ __forceinline__ void gload16(const void* g, void* l) {
  __builtin_amdgcn_global_load_lds(
      (const __attribute__((address_space(1))) void*)g,
      (__attribute__((address_space(3))) void*)l, 16, 0, 0);
}

// ---------------------------------------------------------------------------
// Repack W [256co][256ci][3][3] f32 -> A [co][tap*256+ci] bf16 (tap-major K)
// ---------------------------------------------------------------------------
__global__ void wpack(const float* __restrict__ W, short* __restrict__ A) {
  int tid = blockIdx.x * 256 + threadIdx.x;
  if (tid >= 256 * 2304) return;
  int co = tid / 2304;
  int r  = tid - co * 2304;
  int tap = r >> 8, ci = r & 255;
  A[tid] = f2bf(W[((size_t)(co * 256 + ci)) * 9 + tap]);
}

// ---------------------------------------------------------------------------
// FIR upsample v3: one block per output-row PAIR (p=2t,2t+1), sharing 3
// x-rows. Row-fold in registers at load; col pass per pair.
// hT[b][p'][q'][ci] bf16, p',q' in [0,130), interior = h[p'-1][q'-1].
// ---------------------------------------------------------------------------
__global__ void fir_up(const float* __restrict__ x, short* __restrict__ hT) {
  const int bt = blockIdx.x;
  const int b = bt / 65, t = bt - b * 65;
  const int ci0 = blockIdx.y << 6;
  const int tid = threadIdx.x;

  if (t == 64) {                           // pad rows pp=0 and pp=129
    short* r0 = hT + ((size_t)(b * PH + 0) * PH) * 256 + ci0;
    short* r1 = hT + ((size_t)(b * PH + 129) * PH) * 256 + ci0;
    for (int idx = tid; idx < PH * 32; idx += 256) {
      int qp = idx >> 5, c2 = (idx & 31) * 2;
      *(uint32_t*)&r0[(size_t)qp * 256 + c2] = 0u;
      *(uint32_t*)&r1[(size_t)qp * 256 + c2] = 0u;
    }
    return;
  }

  __shared__ float F[2][64][65];           // folded rows [pair r][j][ci] (+1 pad)
#pragma unroll
  for (int it = 0; it < 4; ++it) {
    int idx = it * 256 + tid;              // ci = idx>>4, j-quad = idx&15
    int ci = idx >> 4, jq = idx & 15;
    const float* base = &x[((size_t)(b * 256 + ci0 + ci) * 64) * 64 + jq * 4];
    f32x4 vm = {0.f, 0.f, 0.f, 0.f}, vp = {0.f, 0.f, 0.f, 0.f};
    f32x4 v0 = *(const f32x4*)(base + (size_t)t * 64);
    if (t >= 1)  vm = *(const f32x4*)(base + (size_t)(t - 1) * 64);
    if (t <= 62) vp = *(const f32x4*)(base + (size_t)(t + 1) * 64);
#pragma unroll
    for (int e = 0; e < 4; ++e) {
      F[0][jq * 4 + e][ci] = 0.25f * vm[e] + 0.75f * v0[e];
      F[1][jq * 4 + e][ci] = 0.75f * v0[e] + 0.25f * vp[e];
    }
  }
  __syncthreads();

  const int c2 = (tid & 31) * 2;
  const int qg = tid >> 5;
#pragma unroll
  for (int r = 0; r < 2; ++r) {
    short* outrow = hT + ((size_t)(b * PH + (2 * t + 1 + r)) * PH) * 256 + ci0;
    for (int qp = qg; qp < PH; qp += 8) {
      uint32_t out = 0u;
      if (qp >= 1 && qp <= 128) {
        int q = qp - 1;
        int par = q & 1;
        int jb = (q >> 1) - 1 + par;
        float wc0 = par ? 0.75f : 0.25f;
        float wc1 = par ? 0.25f : 0.75f;
        float v00 = 0.f, v01 = 0.f, v10 = 0.f, v11 = 0.f;
        if (jb >= 0)     { v00 = F[r][jb][c2];     v01 = F[r][jb][c2 + 1]; }
        if (jb + 1 < 64) { v10 = F[r][jb + 1][c2]; v11 = F[r][jb + 1][c2 + 1]; }
        out = pack2bf(wc0 * v00 + wc1 * v10, wc0 * v01 + wc1 * v11);
      }
      *(uint32_t*)&outrow[(size_t)qp * 256 + c2] = out;
    }
  }
}

// ---------------------------------------------------------------------------
// Implicit GEMM (R11, session-best: 316us, MfmaUtil 45.5%, 0 conflicts):
// BM=128 spatial (one (b,p) row) x BN=128 co, BK=64, 8 waves (2M x 4N),
// wave tile 64q x 32co (acc 4x2 f32x4 = 32 VGPR). LDS 80KB: A ring-3 48KB +
// B dbuf 32KB -> 2 blocks/CU (16 waves/CU). One barrier + one counted
// vmcnt(2) per K-tile (in-flight oldest-first: B(t+1),A(t+2); never 0
// mid-loop). Swizzle phys = L ^ (((L>>7)&7)<<4) both sides (rule 21).
// ---------------------------------------------------------------------------
__global__ __launch_bounds__(512, 4) void conv3x3_gemm(
    const short* __restrict__ hT, const short* __restrict__ Wp,
    const float* __restrict__ bias, float* __restrict__ y) {
  __shared__ short ldsA[3][8192];          // 3 x 16KB [128 rows][64 k]
  __shared__ short ldsB[2][8192];          // 2 x 16KB
  const int tid = threadIdx.x;
  const int lane = tid & 63, w = tid >> 6;
  const int wm = w >> 2, wn = w & 3;       // 2 M-halves x 4 N-quarters

  const int bid = blockIdx.x;
  const int tau = (bid & 7) * 512 + (bid >> 3);  // XCD swizzle, 4096%8==0
  const int mt = tau >> 1, nh = tau & 1;         // M-tile, N-half
  const int b = mt >> 7, p = mt & 127;

  // --- per-lane staging geometry; rule 21 pre-swizzle ---
  const short* srcA[2];
  const short* srcB[2];
#pragma unroll
  for (int i = 0; i < 2; ++i) {
    int o = i * 8192 + w * 1024 + lane * 16;
    int L = o ^ (((o >> 7) & 7) << 4);
    int row = L >> 7, kk = (L & 127) >> 1;       // row in [0,128)
    srcA[i] = hT + ((size_t)((b * PH + p) * PH + row)) * 256 + kk;
    srcB[i] = Wp + (size_t)(nh * 128 + row) * 2304 + kk;
  }

  auto offA = [&](int t) {
    int tap = t >> 2, ci0 = (t & 3) << 6;
    int dm = (tap >= 6) ? 2 : (tap >= 3) ? 1 : 0;
    int dn = tap - 3 * dm;
    return (dm * PH + dn) * 256 + ci0;
  };
  auto offB = [&](int t) { return (t >> 2) * 256 + ((t & 3) << 6); };

  auto stageA = [&](int t) {               // full 16KB tile = 2 issues
    int o = offA(t);
    short* dst = &ldsA[t % 3][0];
#pragma unroll
    for (int i = 0; i < 2; ++i)
      gload16(srcA[i] + o, dst + i * 4096 + w * 512);
  };
  auto stageB = [&](int t) {
    int o = offB(t);
    short* dst = &ldsB[t & 1][0];
#pragma unroll
    for (int i = 0; i < 2; ++i)
      gload16(srcB[i] + o, dst + i * 4096 + w * 512);
  };

  // --- precomputed swizzled frag bases (bytes); reads = base + frag*2048 ---
  int aP[2], bP[2];
#pragma unroll
  for (int ks = 0; ks < 2; ++ks) {
    int La = (wm * 64 + (lane & 15)) * 128 + (lane >> 4) * 16 + ks * 64;
    aP[ks] = La ^ ((lane & 7) << 4);
    int Lb = (wn * 32 + (lane & 15)) * 128 + (lane >> 4) * 16 + ks * 64;
    bP[ks] = Lb ^ ((lane & 7) << 4);
  }

  f32x4 acc[4][2];
#pragma unroll
  for (int m = 0; m < 4; ++m)
#pragma unroll
    for (int n = 0; n < 2; ++n) acc[m][n] = (f32x4){0.f, 0.f, 0.f, 0.f};

  // --- prologue: A(0), B(0), A(1); vmcnt(2) forces tile0, leaves A(1) ---
  stageA(0); stageB(0); stageA(1);
  asm volatile("s_waitcnt vmcnt(2)" ::: "memory");
  __builtin_amdgcn_s_barrier();

  for (int t = 0; t < NT; ++t) {
    const char* LA = (const char*)&ldsA[t % 3][0];
    const char* LB = (const char*)&ldsB[t & 1][0];

    bf16x8 a_[2][4], b_[2][2];
#pragma unroll
    for (int ks = 0; ks < 2; ++ks) {
#pragma unroll
      for (int m = 0; m < 4; ++m) a_[ks][m] = *(const bf16x8*)(LA + aP[ks] + m * 2048);
#pragma unroll
      for (int n = 0; n < 2; ++n) b_[ks][n] = *(const bf16x8*)(LB + bP[ks] + n * 2048);
    }
    if (t + 1 < NT) stageB(t + 1);         // older in issue order
    if (t + 2 < NT) stageA(t + 2);
    asm volatile("s_waitcnt lgkmcnt(0)" ::: "memory");
    __builtin_amdgcn_s_setprio(1);
#pragma unroll
    for (int m = 0; m < 4; ++m)
#pragma unroll
      for (int n = 0; n < 2; ++n) {
        acc[m][n] = __builtin_amdgcn_mfma_f32_16x16x32_bf16(a_[0][m], b_[0][n], acc[m][n], 0, 0, 0);
        acc[m][n] = __builtin_amdgcn_mfma_f32_16x16x32_bf16(a_[1][m], b_[1][n], acc[m][n], 0, 0, 0);
      }
    __builtin_amdgcn_s_setprio(0);
    // gate: force tile t+1 (A(t+1)+B(t+1)); leave A(t+2)'s 2 in flight
    if (t < NT - 2)       asm volatile("s_waitcnt vmcnt(2)" ::: "memory");
    else if (t == NT - 2) asm volatile("s_waitcnt vmcnt(0)" ::: "memory");
    __builtin_amdgcn_s_barrier();
  }

  // ---- epilogue: D row = q, col = co; p fixed ----
#pragma unroll
  for (int n = 0; n < 2; ++n) {
    int co = nh * 128 + wn * 32 + n * 16 + (lane & 15);
    float bv = bias[co];
    float* yp = y + (((size_t)(b * 256 + co)) * 128 + p) * 128;
#pragma unroll
    for (int m = 0; m < 4; ++m) {
      int q0 = wm * 64 + m * 16 + ((lane >> 4) << 2);
      f32x4 vv = acc[m][n];
      vv[0] += bv; vv[1] += bv; vv[2] += bv; vv[3] += bv;
      *(f32x4*)(yp + q0) = vv;
    }
  }
}

// ---------------------------------------------------------------------------
extern "C" void kernel_launch(void* const* d_in, const int* in_sizes, int n_in,
                              void* d_out, int out_size, void* d_ws, size_t ws_size,
                              hipStream_t stream) {
  const float* x    = (const float*)d_in[0];
  const float* W    = (const float*)d_in[1];
  const float* bias = (const float*)d_in[2];
  float* y = (float*)d_out;

  const size_t hT_bytes = (size_t)16 * PH * PH * 256 * 2;   // 138,444,800
  const size_t A_bytes  = (size_t)256 * 2304 * 2;           //   1,179,648
  if (ws_size < hT_bytes + A_bytes) return;

  short* hT = (short*)d_ws;
  short* Wp = (short*)((char*)d_ws + hT_bytes);

  wpack<<<(256 * 2304 + 255) / 256, 256, 0, stream>>>(W, Wp);
  dim3 g1(16 * 65, 4);
  fir_up<<<g1, 256, 0, stream>>>(x, hT);
  conv3x3_gemm<<<4096, 512, 0, stream>>>(hT, Wp, bias, y);
}

// Round 15
// 367.855 us; speedup vs baseline: 1.2091x; 1.0217x over previous
//
#include <hip/hip_runtime.h>
#include <hip/hip_bf16.h>
#include <stdint.h>

typedef __attribute__((ext_vector_type(8))) short bf16x8;
typedef __attribute__((ext_vector_type(4))) float f32x4;

#define PH 130
#define NT 36          // K tiles: 9 taps x 256 ci / BK=64
#define ITERS 18       // 2 K-tiles per iteration

__device__ __forceinline__ short f2bf(float f) {
  uint32_t u = __builtin_bit_cast(uint32_t, f);
  u = (u + 0x7FFFu + ((u >> 16) & 1u)) >> 16;
  return (short)u;
}

__device__ __forceinline__ uint32_t pack2bf(float lo, float hi) {
  return ((uint32_t)(uint16_t)f2bf(hi) << 16) | (uint16_t)f2bf(lo);
}

__device__ __forceinline__ void gload16(const void* g, void* l) {
  __builtin_amdgcn_global_load_lds(
      (const __attribute__((address_space(1))) void*)g,
      (__attribute__((address_space(3))) void*)l, 16, 0, 0);
}

// ---------------------------------------------------------------------------
// Repack W [256co][256ci][3][3] f32 -> A [co][tap*256+ci] bf16 (tap-major K)
// ---------------------------------------------------------------------------
__global__ void wpack(const float* __restrict__ W, short* __restrict__ A) {
  int tid = blockIdx.x * 256 + threadIdx.x;
  if (tid >= 256 * 2304) return;
  int co = tid / 2304;
  int r  = tid - co * 2304;
  int tap = r >> 8, ci = r & 255;
  A[tid] = f2bf(W[((size_t)(co * 256 + ci)) * 9 + tap]);
}

// ---------------------------------------------------------------------------
// FIR upsample v3: one block per output-row PAIR (p=2t,2t+1), sharing 3
// x-rows. Row-fold in registers at load; col pass per pair.
// hT[b][p'][q'][ci] bf16, p',q' in [0,130), interior = h[p'-1][q'-1].
// ---------------------------------------------------------------------------
__global__ void fir_up(const float* __restrict__ x, short* __restrict__ hT) {
  const int bt = blockIdx.x;
  const int b = bt / 65, t = bt - b * 65;
  const int ci0 = blockIdx.y << 6;
  const int tid = threadIdx.x;

  if (t == 64) {                           // pad rows pp=0 and pp=129
    short* r0 = hT + ((size_t)(b * PH + 0) * PH) * 256 + ci0;
    short* r1 = hT + ((size_t)(b * PH + 129) * PH) * 256 + ci0;
    for (int idx = tid; idx < PH * 32; idx += 256) {
      int qp = idx >> 5, c2 = (idx & 31) * 2;
      *(uint32_t*)&r0[(size_t)qp * 256 + c2] = 0u;
      *(uint32_t*)&r1[(size_t)qp * 256 + c2] = 0u;
    }
    return;
  }

  __shared__ float F[2][64][65];           // folded rows [pair r][j][ci] (+1 pad)
#pragma unroll
  for (int it = 0; it < 4; ++it) {
    int idx = it * 256 + tid;              // ci = idx>>4, j-quad = idx&15
    int ci = idx >> 4, jq = idx & 15;
    const float* base = &x[((size_t)(b * 256 + ci0 + ci) * 64) * 64 + jq * 4];
    f32x4 vm = {0.f, 0.f, 0.f, 0.f}, vp = {0.f, 0.f, 0.f, 0.f};
    f32x4 v0 = *(const f32x4*)(base + (size_t)t * 64);
    if (t >= 1)  vm = *(const f32x4*)(base + (size_t)(t - 1) * 64);
    if (t <= 62) vp = *(const f32x4*)(base + (size_t)(t + 1) * 64);
#pragma unroll
    for (int e = 0; e < 4; ++e) {
      F[0][jq * 4 + e][ci] = 0.25f * vm[e] + 0.75f * v0[e];
      F[1][jq * 4 + e][ci] = 0.75f * v0[e] + 0.25f * vp[e];
    }
  }
  __syncthreads();

  const int c2 = (tid & 31) * 2;
  const int qg = tid >> 5;
#pragma unroll
  for (int r = 0; r < 2; ++r) {
    short* outrow = hT + ((size_t)(b * PH + (2 * t + 1 + r)) * PH) * 256 + ci0;
    for (int qp = qg; qp < PH; qp += 8) {
      uint32_t out = 0u;
      if (qp >= 1 && qp <= 128) {
        int q = qp - 1;
        int par = q & 1;
        int jb = (q >> 1) - 1 + par;
        float wc0 = par ? 0.75f : 0.25f;
        float wc1 = par ? 0.25f : 0.75f;
        float v00 = 0.f, v01 = 0.f, v10 = 0.f, v11 = 0.f;
        if (jb >= 0)     { v00 = F[r][jb][c2];     v01 = F[r][jb][c2 + 1]; }
        if (jb + 1 < 64) { v10 = F[r][jb + 1][c2]; v11 = F[r][jb + 1][c2 + 1]; }
        out = pack2bf(wc0 * v00 + wc1 * v10, wc0 * v01 + wc1 * v11);
      }
      *(uint32_t*)&outrow[(size_t)qp * 256 + c2] = out;
    }
  }
}

// ---------------------------------------------------------------------------
// Implicit GEMM, 8-phase schedule (R10 config = session-best TOTAL 368us):
// BM=256 spatial x BN=256 co, BK=64, 8 waves (2M x 4N), grid 1024.
// Iter = 2 K-tiles, 8 phases x 16 MFMA(16x16x32). Stage calendar:
// P1:Ahi(u+1) P3:Blo(u+2) P4:Bhi+Alo(u+2) P5:Ahi(u+2) P7:Blo(u+3)
// P8:Bhi+Alo(u+3). Gates vmcnt(6) at P4/P8 only (never 0 mid-loop).
// Swizzle phys = L ^ (((L>>7)&7)<<4), both-sides (rule 21).
// ---------------------------------------------------------------------------
__global__ __launch_bounds__(512) void conv3x3_gemm(
    const short* __restrict__ hT, const short* __restrict__ Wp,
    const float* __restrict__ bias, float* __restrict__ y) {
  __shared__ short ldsA[2][16384];         // [tile&1][256 rows][64 k]
  __shared__ short ldsB[2][16384];
  const int tid = threadIdx.x;
  const int lane = tid & 63, w = tid >> 6;
  const int wm = w >> 2, wn = w & 3;       // 2 M-waves x 4 N-waves

  const int bid = blockIdx.x;
  const int tau = (bid & 7) * 128 + (bid >> 3);  // XCD swizzle, 1024%8==0
  const int b = tau >> 6, p0 = (tau & 63) * 2;   // 2 output rows p0,p0+1

  // --- per-lane staging geometry; rule 21 pre-swizzle ---
  const short* srcA[4];
  const short* srcB[4];
#pragma unroll
  for (int h = 0; h < 2; ++h)
#pragma unroll
    for (int i = 0; i < 2; ++i) {
      int o = h * 16384 + i * 8192 + w * 1024 + lane * 16;
      int L = o ^ (((o >> 7) & 7) << 4);
      int row = L >> 7, kk = (L & 127) >> 1;
      srcA[h * 2 + i] = hT + ((size_t)((b * PH + p0 + (row >> 7)) * PH + (row & 127))) * 256 + kk;
      srcB[h * 2 + i] = Wp + (size_t)row * 2304 + kk;
    }

  auto offA = [&](int t) {
    int tap = t >> 2, ci0 = (t & 3) << 6;
    int dm = (tap >= 6) ? 2 : (tap >= 3) ? 1 : 0;
    int dn = tap - 3 * dm;
    return (dm * PH + dn) * 256 + ci0;
  };
  auto offB = [&](int t) { return (t >> 2) * 256 + ((t & 3) << 6); };

  auto stageA = [&](int t, int h) {        // one half = 2 gloads
    int o = offA(t);
    short* dst = &ldsA[t & 1][h * 8192];
#pragma unroll
    for (int i = 0; i < 2; ++i)
      gload16(srcA[h * 2 + i] + o, dst + i * 4096 + w * 512);
  };
  auto stageB = [&](int t, int h) {
    int o = offB(t);
    short* dst = &ldsB[t & 1][h * 8192];
#pragma unroll
    for (int i = 0; i < 2; ++i)
      gload16(srcB[h * 2 + i] + o, dst + i * 4096 + w * 512);
  };

  // --- precomputed swizzled frag bases (bytes); reads = base + m*2048 ---
  int aP[2], bP[2];
#pragma unroll
  for (int ks = 0; ks < 2; ++ks) {
    int La = (wm * 128 + (lane & 15)) * 128 + (lane >> 4) * 16 + ks * 64;
    aP[ks] = La ^ ((lane & 7) << 4);
    int Lb = (wn * 64 + (lane & 15)) * 128 + (lane >> 4) * 16 + ks * 64;
    bP[ks] = Lb ^ ((lane & 7) << 4);
  }

  const char* LA0 = (const char*)&ldsA[0][0];
  const char* LB0 = (const char*)&ldsB[0][0];
  const char* LA1 = (const char*)&ldsA[1][0];
  const char* LB1 = (const char*)&ldsB[1][0];

  // --- prologue: tile0 full + tile1 minus Ahi (Ahi(1) comes at P1) ---
  stageA(0, 0); stageB(0, 0); stageB(0, 1); stageA(0, 1);
  stageA(1, 0); stageB(1, 0); stageB(1, 1);
  asm volatile("s_waitcnt vmcnt(6)" ::: "memory");  // tile0 ready
  __builtin_amdgcn_s_barrier();

  f32x4 acc[8][4];
#pragma unroll
  for (int m = 0; m < 8; ++m)
#pragma unroll
    for (int n = 0; n < 4; ++n) acc[m][n] = (f32x4){0.f, 0.f, 0.f, 0.f};

  for (int i = 0; i < ITERS; ++i) {
    const int u = 2 * i, v = u + 1;
    const bool more = (u + 2 < NT);
    bf16x8 a_[2][4], c_[2][4], b_[2][2], b2[2][2];

    // ========== P1: a(u)m0-3 + b(u)n0-1 ; stage Ahi(u+1) ==========
#pragma unroll
    for (int ks = 0; ks < 2; ++ks) {
#pragma unroll
      for (int m = 0; m < 4; ++m) a_[ks][m] = *(const bf16x8*)(LA0 + aP[ks] + m * 2048);
#pragma unroll
      for (int n = 0; n < 2; ++n) b_[ks][n] = *(const bf16x8*)(LB0 + bP[ks] + n * 2048);
    }
    stageA(v, 1);
    __builtin_amdgcn_s_barrier();
    asm volatile("s_waitcnt lgkmcnt(0)" ::: "memory");
    __builtin_amdgcn_s_setprio(1);
#pragma unroll
    for (int m = 0; m < 4; ++m)
#pragma unroll
      for (int n = 0; n < 2; ++n) {
        acc[m][n] = __builtin_amdgcn_mfma_f32_16x16x32_bf16(a_[0][m], b_[0][n], acc[m][n], 0, 0, 0);
        acc[m][n] = __builtin_amdgcn_mfma_f32_16x16x32_bf16(a_[1][m], b_[1][n], acc[m][n], 0, 0, 0);
      }
    __builtin_amdgcn_s_setprio(0);
    __builtin_amdgcn_s_barrier();

    // ========== P2: b(u)n2-3 ==========
#pragma unroll
    for (int ks = 0; ks < 2; ++ks)
#pragma unroll
      for (int n = 0; n < 2; ++n) b2[ks][n] = *(const bf16x8*)(LB0 + bP[ks] + (n + 2) * 2048);
    __builtin_amdgcn_s_barrier();
    asm volatile("s_waitcnt lgkmcnt(0)" ::: "memory");
    __builtin_amdgcn_s_setprio(1);
#pragma unroll
    for (int m = 0; m < 4; ++m)
#pragma unroll
      for (int n = 0; n < 2; ++n) {
        acc[m][n + 2] = __builtin_amdgcn_mfma_f32_16x16x32_bf16(a_[0][m], b2[0][n], acc[m][n + 2], 0, 0, 0);
        acc[m][n + 2] = __builtin_amdgcn_mfma_f32_16x16x32_bf16(a_[1][m], b2[1][n], acc[m][n + 2], 0, 0, 0);
      }
    __builtin_amdgcn_s_setprio(0);
    __builtin_amdgcn_s_barrier();

    // ========== P3: a(u)m4-7 ; stage Blo(u+2) ==========
#pragma unroll
    for (int ks = 0; ks < 2; ++ks)
#pragma unroll
      for (int m = 0; m < 4; ++m) c_[ks][m] = *(const bf16x8*)(LA0 + aP[ks] + (m + 4) * 2048);
    if (more) stageB(u + 2, 0);
    __builtin_amdgcn_s_barrier();
    asm volatile("s_waitcnt lgkmcnt(0)" ::: "memory");
    __builtin_amdgcn_s_setprio(1);
#pragma unroll
    for (int m = 0; m < 4; ++m)
#pragma unroll
      for (int n = 0; n < 2; ++n) {
        acc[m + 4][n] = __builtin_amdgcn_mfma_f32_16x16x32_bf16(c_[0][m], b_[0][n], acc[m + 4][n], 0, 0, 0);
        acc[m + 4][n] = __builtin_amdgcn_mfma_f32_16x16x32_bf16(c_[1][m], b_[1][n], acc[m + 4][n], 0, 0, 0);
      }
    __builtin_amdgcn_s_setprio(0);
    __builtin_amdgcn_s_barrier();

    // ========== P4: stage Bhi(u+2)+Alo(u+2) ; gate vmcnt ==========
    if (more) { stageB(u + 2, 1); stageA(u + 2, 0); }
    __builtin_amdgcn_s_barrier();
    __builtin_amdgcn_s_setprio(1);
#pragma unroll
    for (int m = 0; m < 4; ++m)
#pragma unroll
      for (int n = 0; n < 2; ++n) {
        acc[m + 4][n + 2] = __builtin_amdgcn_mfma_f32_16x16x32_bf16(c_[0][m], b2[0][n], acc[m + 4][n + 2], 0, 0, 0);
        acc[m + 4][n + 2] = __builtin_amdgcn_mfma_f32_16x16x32_bf16(c_[1][m], b2[1][n], acc[m + 4][n + 2], 0, 0, 0);
      }
    __builtin_amdgcn_s_setprio(0);
    if (more) asm volatile("s_waitcnt vmcnt(6)" ::: "memory");
    else      asm volatile("s_waitcnt vmcnt(0)" ::: "memory");
    __builtin_amdgcn_s_barrier();

    // ========== P5: a(v)m0-3 + b(v)n0-1 ; stage Ahi(u+2) ==========
#pragma unroll
    for (int ks = 0; ks < 2; ++ks) {
#pragma unroll
      for (int m = 0; m < 4; ++m) a_[ks][m] = *(const bf16x8*)(LA1 + aP[ks] + m * 2048);
#pragma unroll
      for (int n = 0; n < 2; ++n) b_[ks][n] = *(const bf16x8*)(LB1 + bP[ks] + n * 2048);
    }
    if (more) stageA(u + 2, 1);
    __builtin_amdgcn_s_barrier();
    asm volatile("s_waitcnt lgkmcnt(0)" ::: "memory");
    __builtin_amdgcn_s_setprio(1);
#pragma unroll
    for (int m = 0; m < 4; ++m)
#pragma unroll
      for (int n = 0; n < 2; ++n) {
        acc[m][n] = __builtin_amdgcn_mfma_f32_16x16x32_bf16(a_[0][m], b_[0][n], acc[m][n], 0, 0, 0);
        acc[m][n] = __builtin_amdgcn_mfma_f32_16x16x32_bf16(a_[1][m], b_[1][n], acc[m][n], 0, 0, 0);
      }
    __builtin_amdgcn_s_setprio(0);
    __builtin_amdgcn_s_barrier();

    // ========== P6: b(v)n2-3 ==========
#pragma unroll
    for (int ks = 0; ks < 2; ++ks)
#pragma unroll
      for (int n = 0; n < 2; ++n) b2[ks][n] = *(const bf16x8*)(LB1 + bP[ks] + (n + 2) * 2048);
    __builtin_amdgcn_s_barrier();
    asm volatile("s_waitcnt lgkmcnt(0)" ::: "memory");
    __builtin_amdgcn_s_setprio(1);
#pragma unroll
    for (int m = 0; m < 4; ++m)
#pragma unroll
      for (int n = 0; n < 2; ++n) {
        acc[m][n + 2] = __builtin_amdgcn_mfma_f32_16x16x32_bf16(a_[0][m], b2[0][n], acc[m][n + 2], 0, 0, 0);
        acc[m][n + 2] = __builtin_amdgcn_mfma_f32_16x16x32_bf16(a_[1][m], b2[1][n], acc[m][n + 2], 0, 0, 0);
      }
    __builtin_amdgcn_s_setprio(0);
    __builtin_amdgcn_s_barrier();

    // ========== P7: a(v)m4-7 ; stage Blo(u+3) ==========
#pragma unroll
    for (int ks = 0; ks < 2; ++ks)
#pragma unroll
      for (int m = 0; m < 4; ++m) c_[ks][m] = *(const bf16x8*)(LA1 + aP[ks] + (m + 4) * 2048);
    if (more) stageB(u + 3, 0);
    __builtin_amdgcn_s_barrier();
    asm volatile("s_waitcnt lgkmcnt(0)" ::: "memory");
    __builtin_amdgcn_s_setprio(1);
#pragma unroll
    for (int m = 0; m < 4; ++m)
#pragma unroll
      for (int n = 0; n < 2; ++n) {
        acc[m + 4][n] = __builtin_amdgcn_mfma_f32_16x16x32_bf16(c_[0][m], b_[0][n], acc[m + 4][n], 0, 0, 0);
        acc[m + 4][n] = __builtin_amdgcn_mfma_f32_16x16x32_bf16(c_[1][m], b_[1][n], acc[m + 4][n], 0, 0, 0);
      }
    __builtin_amdgcn_s_setprio(0);
    __builtin_amdgcn_s_barrier();

    // ========== P8: stage Bhi(u+3)+Alo(u+3) ; gate vmcnt(6) ==========
    if (more) { stageB(u + 3, 1); stageA(u + 3, 0); }
    __builtin_amdgcn_s_barrier();
    __builtin_amdgcn_s_setprio(1);
#pragma unroll
    for (int m = 0; m < 4; ++m)
#pragma unroll
      for (int n = 0; n < 2; ++n) {
        acc[m + 4][n + 2] = __builtin_amdgcn_mfma_f32_16x16x32_bf16(c_[0][m], b2[0][n], acc[m + 4][n + 2], 0, 0, 0);
        acc[m + 4][n + 2] = __builtin_amdgcn_mfma_f32_16x16x32_bf16(c_[1][m], b2[1][n], acc[m + 4][n + 2], 0, 0, 0);
      }
    __builtin_amdgcn_s_setprio(0);
    if (more) asm volatile("s_waitcnt vmcnt(6)" ::: "memory");
    __builtin_amdgcn_s_barrier();
  }

  // ---- epilogue: D row = spatial (p0+wm, q), col = co ----
#pragma unroll
  for (int n = 0; n < 4; ++n) {
    int co = wn * 64 + n * 16 + (lane & 15);
    float bv = bias[co];
    float* yp = y + (((size_t)(b * 256 + co)) * 128 + (p0 + wm)) * 128;
#pragma unroll
    for (int m = 0; m < 8; ++m) {
      int q0 = m * 16 + ((lane >> 4) << 2);
      f32x4 vv = acc[m][n];
      vv[0] += bv; vv[1] += bv; vv[2] += bv; vv[3] += bv;
      *(f32x4*)(yp + q0) = vv;
    }
  }
}

// ---------------------------------------------------------------------------
extern "C" void kernel_launch(void* const* d_in, const int* in_sizes, int n_in,
                              void* d_out, int out_size, void* d_ws, size_t ws_size,
                              hipStream_t stream) {
  const float* x    = (const float*)d_in[0];
  const float* W    = (const float*)d_in[1];
  const float* bias = (const float*)d_in[2];
  float* y = (float*)d_out;

  const size_t hT_bytes = (size_t)16 * PH * PH * 256 * 2;   // 138,444,800
  const size_t A_bytes  = (size_t)256 * 2304 * 2;           //   1,179,648
  if (ws_size < hT_bytes + A_bytes) return;

  short* hT = (short*)d_ws;
  short* Wp = (short*)((char*)d_ws + hT_bytes);

  wpack<<<(256 * 2304 + 255) / 256, 256, 0, stream>>>(W, Wp);
  dim3 g1(16 * 65, 4);
  fir_up<<<g1, 256, 0, stream>>>(x, hT);
  conv3x3_gemm<<<1024, 512, 0, stream>>>(hT, Wp, bias, y);
}